// Round 2
// baseline (293.792 us; speedup 1.0000x reference)
//
#include <hip/hip_runtime.h>
#include <math.h>

// CausalSemanticGrouping: key [B,N,D] fp32, slot_embed [K,D] fp32
#define BB 64
#define NN 1024
#define DD 512
#define KK 64
#define CC 1088           // K + N
#define NCT 17            // C / 64
#define INVT 14.285714285714286f   // 1 / 0.07

// d_out: out [B,K,D] fp32 then dots [B,K,C] fp32.
// d_ws (floats): rslot [64] | denomP [B*K*34] | Sp [K*D] u32 | Pp [B*K*C] u32
//   Sp = slot pre-split (hi<<16|lo bf16 bits); Pp = masked exp(dots/T) packed.
//   All regions fully written before read -> no zero-init required.

typedef __bf16 bf16_t;
typedef __bf16 bf16x4 __attribute__((ext_vector_type(4)));
typedef __bf16 bf16x8 __attribute__((ext_vector_type(8)));
typedef float f32x16 __attribute__((ext_vector_type(16)));

__device__ __forceinline__ float waveReduceSum(float v) {
    #pragma unroll
    for (int off = 32; off > 0; off >>= 1) v += __shfl_down(v, off, 64);
    return v;
}
// split x into bf16 hi + bf16 lo (round-nearest), x ~= hi + lo, ~2^-16 rel err
__device__ __forceinline__ void split4(float4 x, bf16x4& hi, bf16x4& lo) {
    float v[4] = {x.x, x.y, x.z, x.w};
    #pragma unroll
    for (int j = 0; j < 4; j++) {
        __bf16 h = (__bf16)v[j];
        hi[j] = h;
        lo[j] = (__bf16)(v[j] - (float)h);
    }
}
__device__ __forceinline__ unsigned packhl(__bf16 h, __bf16 l) {
    return ((unsigned)__builtin_bit_cast(unsigned short, h) << 16)
         | (unsigned)__builtin_bit_cast(unsigned short, l);
}
// unpack 4 packed (hi|lo) words -> hi bf16x4, lo bf16x4
__device__ __forceinline__ void unpack4(uint4 w, bf16x4& hi, bf16x4& lo) {
    unsigned h01 = (w.x >> 16) | (w.y & 0xffff0000u);
    unsigned h23 = (w.z >> 16) | (w.w & 0xffff0000u);
    unsigned l01 = (w.x & 0xffffu) | (w.y << 16);
    unsigned l23 = (w.z & 0xffffu) | (w.w << 16);
    uint2 hw = {h01, h23}, lw = {l01, l23};
    hi = __builtin_bit_cast(bf16x4, hw);
    lo = __builtin_bit_cast(bf16x4, lw);
}

// slot pre-split + slot norms. grid 64 x 64 (1 wave/row).
__global__ __launch_bounds__(64) void k_prep(const float* __restrict__ slot,
                                             unsigned* __restrict__ Sp,
                                             float* __restrict__ rslot) {
    int k = blockIdx.x, lane = threadIdx.x;
    const float4* row = (const float4*)(slot + (size_t)k * DD);
    uint4* orow = (uint4*)(Sp + (size_t)k * DD);
    float s = 0.f;
    #pragma unroll
    for (int i = 0; i < 2; i++) {
        float4 v = row[lane + i * 64];
        s += v.x * v.x + v.y * v.y + v.z * v.z + v.w * v.w;
        bf16x4 h, l;
        split4(v, h, l);
        uint4 w;
        w.x = packhl(h[0], l[0]); w.y = packhl(h[1], l[1]);
        w.z = packhl(h[2], l[2]); w.w = packhl(h[3], l[3]);
        orow[lane + i * 64] = w;
    }
    s = waveReduceSum(s);
    if (lane == 0) rslot[k] = 1.0f / fmaxf(sqrtf(s), 1e-12f);
}

// dots[b, 0:64, ct*64:+64] via split-bf16 32x32x16 MFMA (3 mfma/k-step).
// A staged from pre-split Sp (unpack only); key norms fused from staging regs.
// Epilogue: scaled dots write + packed masked-exp P write + denom partials.
// grid (17, B) x 256.
__global__ __launch_bounds__(256, 3) void k_dots(const float* __restrict__ key,
                                                 const unsigned* __restrict__ Sp,
                                                 const float* __restrict__ rslot,
                                                 float* __restrict__ dots,
                                                 unsigned* __restrict__ Pp,
                                                 float* __restrict__ denomP) {
    __shared__ __align__(16) bf16_t Ahi[64][72], Alo[64][72];
    __shared__ __align__(16) bf16_t Bhi[64][72], Blo[64][72];
    __shared__ float srA[64], srB[64];
    const int b = blockIdx.y, ct = blockIdx.x;
    const int tid = threadIdx.x;
    const int w = tid >> 6, lane = tid & 63;
    const int mw = (w >> 1) * 32, nw = (w & 1) * 32;
    const int g = tid & 15, r0 = tid >> 4;       // staging: rows r0+i*16, cols g*4..+4

    const uint4* ap[4];
    const float* bp[4];
    #pragma unroll
    for (int i = 0; i < 4; i++) {
        int r = r0 + i * 16;
        ap[i] = (const uint4*)(Sp + (size_t)r * DD) + g;   // advance by k0/4 per tile
        int c = ct * 64 + r;
        bp[i] = (c < KK) ? ((const float*)0) : (key + ((size_t)b * NN + (c - KK)) * DD + g * 4);
    }
    // slot-vs-slot columns: ct==0 only; read from Sp too (pre-split), mark via bp==0
    const uint4* bps[4];
    #pragma unroll
    for (int i = 0; i < 4; i++) {
        int c = ct * 64 + r0 + i * 16;
        bps[i] = (c < KK) ? ((const uint4*)(Sp + (size_t)c * DD) + g) : (const uint4*)0;
    }

    if (tid < 64) srA[tid] = rslot[tid];

    uint4 ra[4]; float4 rb[4]; uint4 rbs[4];
    float sqB[4] = {0.f, 0.f, 0.f, 0.f};
    f32x16 acc = {};

    auto load_tile = [&](int k0) {
        #pragma unroll
        for (int i = 0; i < 4; i++) {
            ra[i] = ap[i][k0 >> 2];
            if (bp[i]) rb[i] = *(const float4*)(bp[i] + k0);
            else       rbs[i] = bps[i][k0 >> 2];
        }
    };
    auto stage_tile = [&]() {
        #pragma unroll
        for (int i = 0; i < 4; i++) {
            int r = r0 + i * 16;
            bf16x4 h, l;
            unpack4(ra[i], h, l);
            *(bf16x4*)&Ahi[r][g * 4] = h;
            *(bf16x4*)&Alo[r][g * 4] = l;
            if (bp[i]) {
                sqB[i] += rb[i].x * rb[i].x + rb[i].y * rb[i].y
                        + rb[i].z * rb[i].z + rb[i].w * rb[i].w;
                split4(rb[i], h, l);
            } else {
                unpack4(rbs[i], h, l);
            }
            *(bf16x4*)&Bhi[r][g * 4] = h;
            *(bf16x4*)&Blo[r][g * 4] = l;
        }
    };

    load_tile(0);
    stage_tile();
    __syncthreads();

    for (int k0 = 0; k0 < DD; k0 += 64) {
        if (k0 + 64 < DD) load_tile(k0 + 64);     // in flight across MFMA phase
        #pragma unroll
        for (int kk = 0; kk < 64; kk += 16) {
            bf16x8 ah = *(bf16x8*)&Ahi[mw + (lane & 31)][kk + (lane >> 5) * 8];
            bf16x8 al = *(bf16x8*)&Alo[mw + (lane & 31)][kk + (lane >> 5) * 8];
            bf16x8 bh = *(bf16x8*)&Bhi[nw + (lane & 31)][kk + (lane >> 5) * 8];
            bf16x8 bl = *(bf16x8*)&Blo[nw + (lane & 31)][kk + (lane >> 5) * 8];
            acc = __builtin_amdgcn_mfma_f32_32x32x16_bf16(ah, bh, acc, 0, 0, 0);
            acc = __builtin_amdgcn_mfma_f32_32x32x16_bf16(ah, bl, acc, 0, 0, 0);
            acc = __builtin_amdgcn_mfma_f32_32x32x16_bf16(al, bh, acc, 0, 0, 0);
        }
        __syncthreads();
        if (k0 + 64 < DD) {
            stage_tile();
            __syncthreads();
        }
    }

    // ---- key-row norms: partial sumsq -> LDS reduce (reuse fragment LDS) ----
    float* SB = (float*)&Bhi[0][0];   // [64][17]
    #pragma unroll
    for (int i = 0; i < 4; i++) SB[(r0 + i * 16) * 17 + g] = sqB[i];
    __syncthreads();
    if (tid < 64) {
        int c = ct * 64 + tid;
        if (c < KK) {
            srB[tid] = rslot[c];       // slot column: norm from rslot
        } else {
            float s = 0.f;
            #pragma unroll
            for (int j = 0; j < 16; j++) s += SB[tid * 17 + j];
            srB[tid] = 1.0f / fmaxf(sqrtf(s), 1e-12f);
        }
    }
    __syncthreads();

    // ---- epilogue: scale, write dots + packed P, masked-exp row partials ----
    const int n = nw + (lane & 31);
    const int c = ct * 64 + n;
    const float rn = srB[n];
    #pragma unroll
    for (int reg = 0; reg < 16; reg++) {
        int m = mw + (reg & 3) + 8 * (reg >> 2) + 4 * (lane >> 5);
        float v = acc[reg] * srA[m] * rn;
        dots[((size_t)b * KK + m) * CC + c] = v;
        // mask: slot m attends slots < m (strict) and all keys
        float e = ((c >= KK) || (c < m)) ? __expf(v * INVT) : 0.0f;
        __bf16 hh = (__bf16)e;
        __bf16 ll = (__bf16)(e - (float)hh);
        Pp[((size_t)b * KK + m) * CC + c] = packhl(hh, ll);
        #pragma unroll
        for (int off = 16; off > 0; off >>= 1) e += __shfl_xor(e, off, 64);
        if ((lane & 31) == 0)
            denomP[((size_t)b * KK + m) * 34 + ct * 2 + (w & 1)] = e;
    }
}

// out[b, 0:64, d0:+64] = P x V * invden, A staged from packed Pp (unpack only);
// V transposed+split in LDS; T14 prefetch. grid (8, B) x 256, XCD-bijective
// swizzle so all 8 d-blocks of one b share an XCD L2 (Pp[b] hits L2).
__global__ __launch_bounds__(256, 4) void k_out(const float* __restrict__ key,
                                                const float* __restrict__ slot,
                                                const unsigned* __restrict__ Pp,
                                                const float* __restrict__ denomP,
                                                float* __restrict__ out) {
    __shared__ __align__(16) bf16_t Ahi[64][72], Alo[64][72];
    __shared__ __align__(16) bf16_t Vhi[64][72], Vlo[64][72];   // [d][c] transposed
    __shared__ float sd[64];
    const int flat = blockIdx.x + blockIdx.y * 8;
    const int q = flat >> 6, s = flat & 63;
    const int b = (q << 3) | (s & 7);
    const int d0 = (s >> 3) * 64;
    const int tid = threadIdx.x;
    const int w = tid >> 6, lane = tid & 63;
    const int mw = (w >> 1) * 32, nw = (w & 1) * 32;
    const int g = tid & 15, r0 = tid >> 4;
    const int cpair = tid & 31, dg = tid >> 5;    // V staging roles

    if (tid < 64) {
        const float* dp = denomP + ((size_t)b * KK + tid) * 34;
        float ssum = 0.f;
        #pragma unroll
        for (int j = 0; j < 34; j++) ssum += dp[j];
        sd[tid] = 1.0f / (ssum * (1.0f + 1e-7f));
    }

    const unsigned* adp[4];
    #pragma unroll
    for (int i = 0; i < 4; i++)
        adp[i] = Pp + ((size_t)b * KK + (r0 + i * 16)) * CC + g * 4;

    uint4 ra[4]; float4 v0a, v0b, v1a, v1b;
    f32x16 acc = {};

    auto load_tile = [&](int c0) {
        #pragma unroll
        for (int i = 0; i < 4; i++) ra[i] = *(const uint4*)(adp[i] + c0);
        int c = c0 + 2 * cpair;
        const float* p0 = (c < KK) ? (slot + (size_t)c * DD)
                                   : (key + ((size_t)b * NN + (c - KK)) * DD);
        const float* p1 = (c + 1 < KK) ? (slot + (size_t)(c + 1) * DD)
                                       : (key + ((size_t)b * NN + (c + 1 - KK)) * DD);
        p0 += d0 + dg * 8;
        p1 += d0 + dg * 8;
        v0a = *(const float4*)p0;
        v0b = *(const float4*)(p0 + 4);
        v1a = *(const float4*)p1;
        v1b = *(const float4*)(p1 + 4);
    };
    auto stage_tile = [&]() {
        #pragma unroll
        for (int i = 0; i < 4; i++) {
            int r = r0 + i * 16;
            bf16x4 h, l;
            unpack4(ra[i], h, l);
            *(bf16x4*)&Ahi[r][g * 4] = h;
            *(bf16x4*)&Alo[r][g * 4] = l;
        }
        bf16x4 h0a, l0a, h0b, l0b, h1a, l1a, h1b, l1b;
        split4(v0a, h0a, l0a); split4(v0b, h0b, l0b);
        split4(v1a, h1a, l1a); split4(v1b, h1b, l1b);
        #pragma unroll
        for (int j = 0; j < 8; j++) {
            __bf16 h0 = (j < 4) ? h0a[j] : h0b[j - 4];
            __bf16 l0 = (j < 4) ? l0a[j] : l0b[j - 4];
            __bf16 h1 = (j < 4) ? h1a[j] : h1b[j - 4];
            __bf16 l1 = (j < 4) ? l1a[j] : l1b[j - 4];
            unsigned hw = (unsigned)__builtin_bit_cast(unsigned short, h0)
                        | ((unsigned)__builtin_bit_cast(unsigned short, h1) << 16);
            unsigned lw = (unsigned)__builtin_bit_cast(unsigned short, l0)
                        | ((unsigned)__builtin_bit_cast(unsigned short, l1) << 16);
            *(unsigned*)&Vhi[dg * 8 + j][2 * cpair] = hw;
            *(unsigned*)&Vlo[dg * 8 + j][2 * cpair] = lw;
        }
    };

    load_tile(0);
    stage_tile();
    __syncthreads();

    for (int t = 0; t < NCT; t++) {
        if (t + 1 < NCT) load_tile((t + 1) * 64);   // in flight across MFMA phase
        #pragma unroll
        for (int kk = 0; kk < 64; kk += 16) {
            bf16x8 ah = *(bf16x8*)&Ahi[mw + (lane & 31)][kk + (lane >> 5) * 8];
            bf16x8 al = *(bf16x8*)&Alo[mw + (lane & 31)][kk + (lane >> 5) * 8];
            bf16x8 vh = *(bf16x8*)&Vhi[nw + (lane & 31)][kk + (lane >> 5) * 8];
            bf16x8 vl = *(bf16x8*)&Vlo[nw + (lane & 31)][kk + (lane >> 5) * 8];
            acc = __builtin_amdgcn_mfma_f32_32x32x16_bf16(ah, vh, acc, 0, 0, 0);
            acc = __builtin_amdgcn_mfma_f32_32x32x16_bf16(ah, vl, acc, 0, 0, 0);
            acc = __builtin_amdgcn_mfma_f32_32x32x16_bf16(al, vh, acc, 0, 0, 0);
        }
        __syncthreads();
        if (t + 1 < NCT) {
            stage_tile();
            __syncthreads();
        }
    }

    const int d = d0 + nw + (lane & 31);
    #pragma unroll
    for (int reg = 0; reg < 16; reg++) {
        int m = mw + (reg & 3) + 8 * (reg >> 2) + 4 * (lane >> 5);
        out[((size_t)b * KK + m) * DD + d] = acc[reg] * sd[m];
    }
}

extern "C" void kernel_launch(void* const* d_in, const int* in_sizes, int n_in,
                              void* d_out, int out_size, void* d_ws, size_t ws_size,
                              hipStream_t stream) {
    const float* key  = (const float*)d_in[0];   // [B, N, D]
    const float* slot = (const float*)d_in[1];   // [K, D]
    float* out  = (float*)d_out;                        // [B, K, D]
    float* dots = out + (size_t)BB * KK * DD;           // [B, K, C]
    float* ws = (float*)d_ws;
    float* rslot = ws;                                  // [64]
    float* denomP = ws + 64;                            // [B*K*34]
    unsigned* Sp = (unsigned*)(ws + 64 + (size_t)BB * KK * 34);   // [K*D]
    unsigned* Pp = Sp + (size_t)KK * DD;                          // [B*K*C]

    k_prep<<<dim3(KK), dim3(64), 0, stream>>>(slot, Sp, rslot);
    k_dots<<<dim3(NCT, BB), dim3(256), 0, stream>>>(key, Sp, rslot, dots, Pp, denomP);
    k_out<<<dim3(DD / 64, BB), dim3(256), 0, stream>>>(key, slot, Pp, denomP, out);
}

// Round 3
// 257.128 us; speedup vs baseline: 1.1426x; 1.1426x over previous
//
#include <hip/hip_runtime.h>
#include <math.h>

// CausalSemanticGrouping: key [B,N,D] fp32, slot_embed [K,D] fp32
#define BB 64
#define NN 1024
#define DD 512
#define KK 64
#define CC 1088           // K + N
#define NCT 17            // C / 64
#define INVT 14.285714285714286f   // 1 / 0.07

// d_out: out [B,K,D] fp32 then dots [B,K,C] fp32.
// d_ws (floats): denomP [B*K*34] | Pp [B*K*C] u32 (packed hi|lo bf16 of exp).
//   All regions fully written before read -> no zero-init required.

typedef __bf16 bf16_t;
typedef __bf16 bf16x4 __attribute__((ext_vector_type(4)));
typedef __bf16 bf16x8 __attribute__((ext_vector_type(8)));
typedef float f32x16 __attribute__((ext_vector_type(16)));

// async global->LDS, 16B per lane; lds base wave-uniform, HW adds lane*16
__device__ __forceinline__ void gload16(const void* src, void* lds) {
    __builtin_amdgcn_global_load_lds(
        (const __attribute__((address_space(1))) void*)src,
        (__attribute__((address_space(3))) void*)lds, 16, 0, 0);
}

// split x into bf16 hi + bf16 lo (round-nearest), x ~= hi + lo, ~2^-16 rel err
__device__ __forceinline__ void split4(float4 x, bf16x4& hi, bf16x4& lo) {
    float v[4] = {x.x, x.y, x.z, x.w};
    #pragma unroll
    for (int j = 0; j < 4; j++) {
        __bf16 h = (__bf16)v[j];
        hi[j] = h;
        lo[j] = (__bf16)(v[j] - (float)h);
    }
}
__device__ __forceinline__ bf16x8 cat8(bf16x4 a, bf16x4 b) {
    union { bf16x4 h[2]; bf16x8 v; } u;
    u.h[0] = a; u.h[1] = b;
    return u.v;
}
__device__ __forceinline__ unsigned packhl(__bf16 h, __bf16 l) {
    return ((unsigned)__builtin_bit_cast(unsigned short, h) << 16)
         | (unsigned)__builtin_bit_cast(unsigned short, l);
}
// unpack 4 packed (hi|lo) words -> hi bf16x4, lo bf16x4
__device__ __forceinline__ void unpack4(uint4 w, bf16x4& hi, bf16x4& lo) {
    unsigned h01 = (w.x >> 16) | (w.y & 0xffff0000u);
    unsigned h23 = (w.z >> 16) | (w.w & 0xffff0000u);
    unsigned l01 = (w.x & 0xffffu) | (w.y << 16);
    unsigned l23 = (w.z & 0xffffu) | (w.w << 16);
    uint2 hw = {h01, h23}, lw = {l01, l23};
    hi = __builtin_bit_cast(bf16x4, hw);
    lo = __builtin_bit_cast(bf16x4, lw);
}

// dots[b, 0:64, ct*64:+64] via split-bf16 32x32x16 MFMA.
// B (slot/key rows) staged raw f32 via global_load_lds, XOR-swizzled, dbuf;
// A (slot) direct global loads (L2-hot, 128KB total); split-on-read.
// Norms fused: one sumsq role per wave from the fragment values.
// Epilogue: dots + packed masked-exp Pp + denomP partials. grid (17, B) x 256.
__global__ __launch_bounds__(256, 3) void k_dots(const float* __restrict__ key,
                                                 const float* __restrict__ slot,
                                                 float* __restrict__ dots,
                                                 unsigned* __restrict__ Pp,
                                                 float* __restrict__ denomP) {
    __shared__ __align__(16) float Bt[2][64][64];   // 32 KB, slot-swizzled
    __shared__ float srA[64], srB[64];
    const int b = blockIdx.y, ct = blockIdx.x;
    const int tid = threadIdx.x;
    const int w = tid >> 6, lane = tid & 63;
    const int mw = (w >> 1) * 32, nw = (w & 1) * 32;
    const int half = lane >> 5;
    const int rq = tid >> 4, p = tid & 15;   // staging row-in-16 / slot position
    const int pswz = p ^ rq;                 // (i*16+rq)&15 == rq for all i

    // staging source: block-uniform slot (ct==0) or key rows; pre-swizzled col
    const float* srcbase = (ct == 0)
        ? (slot + (size_t)rq * DD + pswz * 4)
        : (key + ((size_t)b * NN + (size_t)(ct - 1) * 64 + rq) * DD + pswz * 4);
    char* ldsw0 = (char*)&Bt[0][0][0] + w * 1024;
    char* ldsw1 = (char*)&Bt[1][0][0] + w * 1024;

    const float* arow = slot + (size_t)(mw + (lane & 31)) * DD + half * 8;
    const int brow = nw + (lane & 31);
    const int bsw = lane & 15;               // brow & 15
    const bool doB = (w == 0) || (w == 3);   // sumsq role: B rows vs A rows

    f32x16 acc = {};
    float sq = 0.f;

    #pragma unroll
    for (int i = 0; i < 4; i++)
        gload16(srcbase + (size_t)i * 16 * DD, ldsw0 + i * 4096);
    __syncthreads();

    for (int t = 0; t < 8; t++) {
        const int cur = t & 1;
        if (t + 1 < 8) {
            const float* s2 = srcbase + (t + 1) * 64;
            char* l2 = cur ? ldsw0 : ldsw1;
            #pragma unroll
            for (int i = 0; i < 4; i++)
                gload16(s2 + (size_t)i * 16 * DD, l2 + i * 4096);
        }
        const int kbase = t * 64;
        #pragma unroll
        for (int kk = 0; kk < 64; kk += 16) {
            float4 a0 = *(const float4*)(arow + kbase + kk);
            float4 a1 = *(const float4*)(arow + kbase + kk + 4);
            const int s0 = (kk >> 2) + half * 2;
            float4 b0 = *(const float4*)&Bt[cur][brow][((s0) ^ bsw) << 2];
            float4 b1 = *(const float4*)&Bt[cur][brow][((s0 + 1) ^ bsw) << 2];
            if (doB)
                sq += b0.x*b0.x + b0.y*b0.y + b0.z*b0.z + b0.w*b0.w
                    + b1.x*b1.x + b1.y*b1.y + b1.z*b1.z + b1.w*b1.w;
            else
                sq += a0.x*a0.x + a0.y*a0.y + a0.z*a0.z + a0.w*a0.w
                    + a1.x*a1.x + a1.y*a1.y + a1.z*a1.z + a1.w*a1.w;
            bf16x4 h0, l0, h1, l1;
            split4(a0, h0, l0); split4(a1, h1, l1);
            bf16x8 ah = cat8(h0, h1), al = cat8(l0, l1);
            split4(b0, h0, l0); split4(b1, h1, l1);
            bf16x8 bh = cat8(h0, h1), bl = cat8(l0, l1);
            acc = __builtin_amdgcn_mfma_f32_32x32x16_bf16(ah, bh, acc, 0, 0, 0);
            acc = __builtin_amdgcn_mfma_f32_32x32x16_bf16(ah, bl, acc, 0, 0, 0);
            acc = __builtin_amdgcn_mfma_f32_32x32x16_bf16(al, bh, acc, 0, 0, 0);
        }
        __syncthreads();   // drains vmcnt: next-tile stage complete, reads done
    }

    // ---- norms: combine lane halves; each wave owns one 32-row range ----
    float st = sq + __shfl_xor(sq, 32, 64);
    if (lane < 32) {
        float rv = 1.0f / fmaxf(sqrtf(st), 1e-12f);
        if (w == 0)      srB[lane]      = rv;   // B rows 0-31
        else if (w == 3) srB[32 + lane] = rv;   // B rows 32-63
        else if (w == 1) srA[lane]      = rv;   // A rows 0-31
        else             srA[32 + lane] = rv;   // A rows 32-63
    }
    __syncthreads();

    // ---- epilogue: scale, write dots + packed P, masked-exp row partials ----
    const int n = nw + (lane & 31);
    const int c = ct * 64 + n;
    const float rn = srB[n];
    #pragma unroll
    for (int reg = 0; reg < 16; reg++) {
        int m = mw + (reg & 3) + 8 * (reg >> 2) + 4 * half;
        float v = acc[reg] * srA[m] * rn;
        dots[((size_t)b * KK + m) * CC + c] = v;
        // mask: slot m attends slots < m (strict) and all keys
        float e = ((c >= KK) || (c < m)) ? __expf(v * INVT) : 0.0f;
        __bf16 hh = (__bf16)e;
        __bf16 ll = (__bf16)(e - (float)hh);
        Pp[((size_t)b * KK + m) * CC + c] = packhl(hh, ll);
        #pragma unroll
        for (int off = 16; off > 0; off >>= 1) e += __shfl_xor(e, off, 64);
        if ((lane & 31) == 0)
            denomP[((size_t)b * KK + m) * 34 + ct * 2 + (w & 1)] = e;
    }
}

// out[b, 0:64, d0:+64] = (P x V) * invden. P staged from packed Pp via
// global_load_lds (unpack on read); V staged raw f32, transposed on LDS read
// (column reads conflict-free); dbuf + XCD-bijective swizzle. grid (8,B) x 256.
__global__ __launch_bounds__(256, 2) void k_out(const float* __restrict__ key,
                                                const float* __restrict__ slot,
                                                const unsigned* __restrict__ Pp,
                                                const float* __restrict__ denomP,
                                                float* __restrict__ out) {
    __shared__ __align__(16) unsigned Pt[2][64][64];  // 32 KB packed P
    __shared__ __align__(16) float    Vt[2][64][64];  // 32 KB raw V rows
    __shared__ float sd[64];
    const int flat = blockIdx.x + blockIdx.y * 8;
    const int q = flat >> 6, s = flat & 63;
    const int b = (q << 3) | (s & 7);       // 8 d-blocks of b on one XCD
    const int d0 = (s >> 3) * 64;
    const int tid = threadIdx.x;
    const int w = tid >> 6, lane = tid & 63;
    const int mw = (w >> 1) * 32, nw = (w & 1) * 32;
    const int half = lane >> 5;
    const int rq = tid >> 4, p = tid & 15;
    const int pswz = p ^ rq;

    if (tid < 64) {
        const float* dp = denomP + ((size_t)b * KK + tid) * 34;
        float ss = 0.f;
        #pragma unroll
        for (int j = 0; j < 34; j++) ss += dp[j];
        sd[tid] = 1.0f / (ss * (1.0f + 1e-7f));
    }

    const unsigned* psrc = Pp + ((size_t)b * KK + rq) * CC + pswz * 4;
    char* ldsP0 = (char*)&Pt[0][0][0] + w * 1024;
    char* ldsP1 = (char*)&Pt[1][0][0] + w * 1024;
    char* ldsV0 = (char*)&Vt[0][0][0] + w * 1024;
    char* ldsV1 = (char*)&Vt[1][0][0] + w * 1024;

    auto stage = [&](int buf, int t) {
        const int c0 = t * 64;
        char* lp = buf ? ldsP1 : ldsP0;
        char* lv = buf ? ldsV1 : ldsV0;
        #pragma unroll
        for (int i = 0; i < 4; i++)
            gload16(psrc + c0 + (size_t)i * 16 * CC, lp + i * 4096);
        const float* vb = (t == 0)
            ? (slot + (size_t)rq * DD + d0 + pswz * 4)
            : (key + ((size_t)b * NN + (size_t)(t - 1) * 64 + rq) * DD + d0 + pswz * 4);
        #pragma unroll
        for (int i = 0; i < 4; i++)
            gload16(vb + (size_t)i * 16 * DD, lv + i * 4096);
    };

    const int arow = mw + (lane & 31);
    const int asw = lane & 15;              // arow & 15
    const int d = nw + (lane & 31);
    const int dslot = d >> 2, dword = d & 3;

    f32x16 acc = {};
    stage(0, 0);
    __syncthreads();

    for (int t = 0; t < NCT; t++) {
        const int cur = t & 1;
        if (t + 1 < NCT) stage(cur ^ 1, t + 1);
        #pragma unroll
        for (int kk = 0; kk < 64; kk += 16) {
            const int s0 = (kk >> 2) + half * 2;
            uint4 p0 = *(const uint4*)&Pt[cur][arow][((s0) ^ asw) << 2];
            uint4 p1 = *(const uint4*)&Pt[cur][arow][((s0 + 1) ^ asw) << 2];
            bf16x4 h0, l0, h1, l1;
            unpack4(p0, h0, l0); unpack4(p1, h1, l1);
            bf16x8 ah = cat8(h0, h1), al = cat8(l0, l1);
            bf16x8 vh, vl;
            #pragma unroll
            for (int j = 0; j < 8; j++) {
                const int rv = kk + half * 8 + j;
                float f = Vt[cur][rv][((dslot ^ (rv & 15)) << 2) + dword];
                __bf16 fh = (__bf16)f;
                vh[j] = fh;
                vl[j] = (__bf16)(f - (float)fh);
            }
            acc = __builtin_amdgcn_mfma_f32_32x32x16_bf16(ah, vh, acc, 0, 0, 0);
            acc = __builtin_amdgcn_mfma_f32_32x32x16_bf16(ah, vl, acc, 0, 0, 0);
            acc = __builtin_amdgcn_mfma_f32_32x32x16_bf16(al, vh, acc, 0, 0, 0);
        }
        __syncthreads();
    }

    const int dd = d0 + d;
    #pragma unroll
    for (int reg = 0; reg < 16; reg++) {
        int m = mw + (reg & 3) + 8 * (reg >> 2) + 4 * half;
        out[((size_t)b * KK + m) * DD + dd] = acc[reg] * sd[m];
    }
}

extern "C" void kernel_launch(void* const* d_in, const int* in_sizes, int n_in,
                              void* d_out, int out_size, void* d_ws, size_t ws_size,
                              hipStream_t stream) {
    const float* key  = (const float*)d_in[0];   // [B, N, D]
    const float* slot = (const float*)d_in[1];   // [K, D]
    float* out  = (float*)d_out;                        // [B, K, D]
    float* dots = out + (size_t)BB * KK * DD;           // [B, K, C]
    float* ws = (float*)d_ws;
    float* denomP = ws;                                 // [B*K*34]
    unsigned* Pp = (unsigned*)(ws + (size_t)BB * KK * 34);  // [B*K*C]

    k_dots<<<dim3(NCT, BB), dim3(256), 0, stream>>>(key, slot, dots, Pp, denomP);
    k_out<<<dim3(DD / 64, BB), dim3(256), 0, stream>>>(key, slot, Pp, denomP, out);
}